// Round 1
// baseline (806.441 us; speedup 1.0000x reference)
//
#include <hip/hip_runtime.h>
#include <hip/hip_bf16.h>

#define T_TOK 1024
#define HDIM  2048
#define NEXP  8
#define IDIM  1408
#define SIDIM 5632
#define MAXSLOTS 40

typedef __attribute__((ext_vector_type(8))) short bf16x8;
typedef __attribute__((ext_vector_type(4))) float f32x4;

__device__ __forceinline__ unsigned f2bf(float x) {
    unsigned u = __float_as_uint(x);
    return (u + 0x7fffu + ((u >> 16) & 1u)) >> 16;
}
__device__ __forceinline__ unsigned pack2(float a, float b) {
    return f2bf(a) | (f2bf(b) << 16);
}

// ---------------- Router: logits, softmax, top-2, token lists ----------------
__global__ __launch_bounds__(256) void router_kernel(
    const float* __restrict__ hs, const float* __restrict__ gw,
    const float* __restrict__ sgw, float* __restrict__ out_logits,
    float* __restrict__ w_dense, float* __restrict__ sgate,
    int* __restrict__ counts, int* __restrict__ tok_list)
{
    const int t = blockIdx.x;
    const int tid = threadIdx.x;
    const float* h = hs + (size_t)t * HDIM;
    float acc[9];
#pragma unroll
    for (int e = 0; e < 9; ++e) acc[e] = 0.f;
    for (int i = tid; i < HDIM; i += 256) {
        float hv = h[i];
        const float4* g4 = (const float4*)(gw + (size_t)i * NEXP);
        float4 g0 = g4[0], g1 = g4[1];
        acc[0] += hv * g0.x; acc[1] += hv * g0.y;
        acc[2] += hv * g0.z; acc[3] += hv * g0.w;
        acc[4] += hv * g1.x; acc[5] += hv * g1.y;
        acc[6] += hv * g1.z; acc[7] += hv * g1.w;
        acc[8] += hv * sgw[i];
    }
#pragma unroll
    for (int e = 0; e < 9; ++e)
        for (int off = 32; off > 0; off >>= 1)
            acc[e] += __shfl_down(acc[e], off, 64);
    __shared__ float lds[4][9];
    const int wid = tid >> 6, lane = tid & 63;
    if (lane == 0)
        for (int e = 0; e < 9; ++e) lds[wid][e] = acc[e];
    __syncthreads();
    if (tid == 0) {
        float l[9];
        for (int e = 0; e < 9; ++e)
            l[e] = lds[0][e] + lds[1][e] + lds[2][e] + lds[3][e];
        for (int e = 0; e < NEXP; ++e) out_logits[(size_t)t * NEXP + e] = l[e];
        float m = l[0];
        for (int e = 1; e < NEXP; ++e) m = fmaxf(m, l[e]);
        float p[NEXP], s = 0.f;
        for (int e = 0; e < NEXP; ++e) { p[e] = expf(l[e] - m); s += p[e]; }
        float inv = 1.f / s;
        for (int e = 0; e < NEXP; ++e) p[e] *= inv;
        int e0 = 0;
        for (int e = 1; e < NEXP; ++e) if (p[e] > p[e0]) e0 = e;
        int e1 = (e0 == 0) ? 1 : 0;
        for (int e = 0; e < NEXP; ++e) if (e != e0 && p[e] > p[e1]) e1 = e;
        for (int e = 0; e < NEXP; ++e)
            w_dense[(size_t)t * NEXP + e] = (e == e0) ? p[e0] : ((e == e1) ? p[e1] : 0.f);
        sgate[t] = 1.f / (1.f + expf(-l[8]));
        int p0 = atomicAdd(&counts[e0], 1); tok_list[e0 * T_TOK + p0] = t;
        int p1 = atomicAdd(&counts[e1], 1); tok_list[e1 * T_TOK + p1] = t;
    }
}

// ---------------- Slot table: per-expert 64-row M tiles ----------------
__global__ __launch_bounds__(64) void slot_kernel(
    const int* __restrict__ counts, int* __restrict__ slot_e,
    int* __restrict__ slot_rb, int* __restrict__ nslots)
{
    if (threadIdx.x == 0 && blockIdx.x == 0) {
        int ns = 0;
        for (int e = 0; e < NEXP; ++e)
            for (int b = 0; b < counts[e]; b += 64) {
                slot_e[ns] = e; slot_rb[ns] = b; ++ns;
            }
        nslots[0] = ns;
    }
}

// ---------------- Gate+Up GEMM: Y = silu(X@Wg) * (X@Wu), bf16 out ----------------
// mode 0: routed (rows gathered via tok_list), mode 1: shared (identity rows)
__global__ __launch_bounds__(256) void gateup_kernel(
    const float* __restrict__ X,
    const float* __restrict__ Wg_all, const float* __restrict__ Wu_all,
    long long estride, unsigned short* __restrict__ Y, int N, int K,
    const int* __restrict__ slot_e, const int* __restrict__ slot_rb,
    const int* __restrict__ counts, const int* __restrict__ nslots,
    const int* __restrict__ tok_list, int mode)
{
    const int slot = blockIdx.y;
    if (mode == 0 && slot >= nslots[0]) return;
    const int n0 = blockIdx.x * 64;
    const int e = (mode == 0) ? slot_e[slot] : 0;
    const int rowbase = (mode == 0) ? slot_rb[slot] : 0;
    const float* __restrict__ Wg = Wg_all + (size_t)e * estride;
    const float* __restrict__ Wu = Wu_all + (size_t)e * estride;
    const int tid = threadIdx.x;
    const int lane = tid & 63;
    const int wid = tid >> 6;
    const int wr = (wid >> 1) * 32;
    const int wc = (wid & 1) * 32;

    __shared__ int ltok[64];
    __shared__ __align__(16) unsigned Xl[64 * 20];   // [row][k-pair], stride 20 words
    __shared__ unsigned Wgl[64 * 17];                // [n][k-pair], stride 17 words
    __shared__ unsigned Wul[64 * 17];

    if (tid < 64) {
        int tg;
        if (mode == 0) {
            int cnt = counts[e];
            tg = (rowbase + tid < cnt) ? tok_list[e * T_TOK + rowbase + tid] : -1;
        } else {
            tg = slot * 64 + tid;
        }
        ltok[tid] = tg;
    }
    __syncthreads();

    f32x4 ag[2][2], au[2][2];
#pragma unroll
    for (int a = 0; a < 2; ++a)
#pragma unroll
        for (int b = 0; b < 2; ++b) {
            ag[a][b] = f32x4{0.f, 0.f, 0.f, 0.f};
            au[a][b] = f32x4{0.f, 0.f, 0.f, 0.f};
        }

    const int xr = tid >> 2;          // 0..63 row
    const int xk = (tid & 3) * 8;     // k offset 0/8/16/24
    const int tokr = ltok[xr];
    const int wl = tid & 15;          // n-chunk
    const int wq = tid >> 4;          // k-pair 0..15
    const int kg = lane >> 4;         // 0..3
    const int fm = lane & 15;

    for (int k0 = 0; k0 < K; k0 += 32) {
        float4 x0, x1;
        if (tokr >= 0) {
            const float4* s4 = (const float4*)(X + (size_t)tokr * K + k0 + xk);
            x0 = s4[0]; x1 = s4[1];
        } else {
            x0 = make_float4(0.f, 0.f, 0.f, 0.f); x1 = x0;
        }
        unsigned* xw = Xl + xr * 20 + (xk >> 1);
        xw[0] = pack2(x0.x, x0.y); xw[1] = pack2(x0.z, x0.w);
        xw[2] = pack2(x1.x, x1.y); xw[3] = pack2(x1.z, x1.w);
        {
            const float* p0 = Wg + (size_t)(k0 + wq * 2) * N + n0 + wl * 4;
            float4 a = *(const float4*)p0;
            float4 b = *(const float4*)(p0 + N);
            unsigned* ww = Wgl + (wl * 4) * 17 + wq;
            ww[0]  = pack2(a.x, b.x); ww[17] = pack2(a.y, b.y);
            ww[34] = pack2(a.z, b.z); ww[51] = pack2(a.w, b.w);
        }
        {
            const float* p0 = Wu + (size_t)(k0 + wq * 2) * N + n0 + wl * 4;
            float4 a = *(const float4*)p0;
            float4 b = *(const float4*)(p0 + N);
            unsigned* ww = Wul + (wl * 4) * 17 + wq;
            ww[0]  = pack2(a.x, b.x); ww[17] = pack2(a.y, b.y);
            ww[34] = pack2(a.z, b.z); ww[51] = pack2(a.w, b.w);
        }
        __syncthreads();

        bf16x8 afrag[2];
        afrag[0] = *(const bf16x8*)(Xl + (wr + fm) * 20 + kg * 4);
        afrag[1] = *(const bf16x8*)(Xl + (wr + 16 + fm) * 20 + kg * 4);
#pragma unroll
        for (int nt = 0; nt < 2; ++nt) {
            const int nn = wc + nt * 16 + fm;
            union { unsigned u[4]; bf16x8 v; } bg, bu;
            const int base = nn * 17 + kg * 4;
#pragma unroll
            for (int j = 0; j < 4; ++j) { bg.u[j] = Wgl[base + j]; bu.u[j] = Wul[base + j]; }
#pragma unroll
            for (int mt = 0; mt < 2; ++mt) {
                ag[mt][nt] = __builtin_amdgcn_mfma_f32_16x16x32_bf16(afrag[mt], bg.v, ag[mt][nt], 0, 0, 0);
                au[mt][nt] = __builtin_amdgcn_mfma_f32_16x16x32_bf16(afrag[mt], bu.v, au[mt][nt], 0, 0, 0);
            }
        }
        __syncthreads();
    }

#pragma unroll
    for (int mt = 0; mt < 2; ++mt)
#pragma unroll
        for (int nt = 0; nt < 2; ++nt) {
            const int cl = n0 + wc + nt * 16 + fm;
#pragma unroll
            for (int i = 0; i < 4; ++i) {
                const int rt = wr + mt * 16 + kg * 4 + i;
                float g = ag[mt][nt][i], u = au[mt][nt][i];
                float yv = g / (1.f + expf(-g)) * u;
                Y[(size_t)(slot * 64 + rt) * N + cl] = (unsigned short)f2bf(yv);
            }
        }
}

// ---------------- Down GEMM: out[t] += w * (Y @ Wd) ----------------
__global__ __launch_bounds__(256) void down_kernel(
    const unsigned short* __restrict__ Yb, const float* __restrict__ Wd_all,
    long long estride, float* __restrict__ out, int K,
    const int* __restrict__ slot_e, const int* __restrict__ slot_rb,
    const int* __restrict__ counts, const int* __restrict__ nslots,
    const int* __restrict__ tok_list, const float* __restrict__ w_dense,
    const float* __restrict__ sgate, int mode)
{
    const int slot = blockIdx.y;
    if (mode == 0 && slot >= nslots[0]) return;
    const int n0 = blockIdx.x * 64;
    const int e = (mode == 0) ? slot_e[slot] : 0;
    const int rowbase = (mode == 0) ? slot_rb[slot] : 0;
    const float* __restrict__ Wd = Wd_all + (size_t)e * estride;
    const int tid = threadIdx.x;
    const int lane = tid & 63;
    const int wid = tid >> 6;
    const int wr = (wid >> 1) * 32;
    const int wc = (wid & 1) * 32;

    __shared__ int ltok[64];
    __shared__ float lw[64];
    __shared__ __align__(16) unsigned Xl[64 * 20];
    __shared__ unsigned Wdl[64 * 17];

    if (tid < 64) {
        int tg; float wv;
        if (mode == 0) {
            int cnt = counts[e];
            if (rowbase + tid < cnt) {
                tg = tok_list[e * T_TOK + rowbase + tid];
                wv = w_dense[(size_t)tg * NEXP + e];
            } else { tg = -1; wv = 0.f; }
        } else {
            tg = slot * 64 + tid; wv = sgate[tg];
        }
        ltok[tid] = tg; lw[tid] = wv;
    }
    __syncthreads();

    f32x4 acc[2][2];
#pragma unroll
    for (int a = 0; a < 2; ++a)
#pragma unroll
        for (int b = 0; b < 2; ++b) acc[a][b] = f32x4{0.f, 0.f, 0.f, 0.f};

    const int xr = tid >> 2;
    const int xk = (tid & 3) * 8;
    const unsigned short* ysrc = Yb + (size_t)(slot * 64 + xr) * K + xk;
    const int wl = tid & 15;
    const int wq = tid >> 4;
    const int kg = lane >> 4;
    const int fm = lane & 15;

    for (int k0 = 0; k0 < K; k0 += 32) {
        uint4 v = *(const uint4*)(ysrc + k0);
        unsigned* xw = Xl + xr * 20 + (xk >> 1);
        xw[0] = v.x; xw[1] = v.y; xw[2] = v.z; xw[3] = v.w;
        {
            const float* p0 = Wd + (size_t)(k0 + wq * 2) * HDIM + n0 + wl * 4;
            float4 a = *(const float4*)p0;
            float4 b = *(const float4*)(p0 + HDIM);
            unsigned* ww = Wdl + (wl * 4) * 17 + wq;
            ww[0]  = pack2(a.x, b.x); ww[17] = pack2(a.y, b.y);
            ww[34] = pack2(a.z, b.z); ww[51] = pack2(a.w, b.w);
        }
        __syncthreads();
        bf16x8 afrag[2];
        afrag[0] = *(const bf16x8*)(Xl + (wr + fm) * 20 + kg * 4);
        afrag[1] = *(const bf16x8*)(Xl + (wr + 16 + fm) * 20 + kg * 4);
#pragma unroll
        for (int nt = 0; nt < 2; ++nt) {
            const int nn = wc + nt * 16 + fm;
            union { unsigned u[4]; bf16x8 v; } bd;
            const int base = nn * 17 + kg * 4;
#pragma unroll
            for (int j = 0; j < 4; ++j) bd.u[j] = Wdl[base + j];
#pragma unroll
            for (int mt = 0; mt < 2; ++mt)
                acc[mt][nt] = __builtin_amdgcn_mfma_f32_16x16x32_bf16(afrag[mt], bd.v, acc[mt][nt], 0, 0, 0);
        }
        __syncthreads();
    }

#pragma unroll
    for (int mt = 0; mt < 2; ++mt)
#pragma unroll
        for (int nt = 0; nt < 2; ++nt) {
            const int cl = n0 + wc + nt * 16 + fm;
#pragma unroll
            for (int i = 0; i < 4; ++i) {
                const int rt = wr + mt * 16 + kg * 4 + i;
                int tg = ltok[rt];
                if (tg >= 0)
                    atomicAdd(out + (size_t)tg * HDIM + cl, lw[rt] * acc[mt][nt][i]);
            }
        }
}

extern "C" void kernel_launch(void* const* d_in, const int* in_sizes, int n_in,
                              void* d_out, int out_size, void* d_ws, size_t ws_size,
                              hipStream_t stream)
{
    const float* hs  = (const float*)d_in[0];
    const float* gw  = (const float*)d_in[1];
    const float* wg  = (const float*)d_in[2];
    const float* wu  = (const float*)d_in[3];
    const float* wd  = (const float*)d_in[4];
    const float* swg = (const float*)d_in[5];
    const float* swu = (const float*)d_in[6];
    const float* swd = (const float*)d_in[7];
    const float* sgw = (const float*)d_in[8];
    float* out = (float*)d_out;
    char* ws = (char*)d_ws;

    float* w_dense   = (float*)(ws);                    // 32768 B
    float* sgate     = (float*)(ws + 32768);            // 4096 B
    int*   counts    = (int*)(ws + 36864);              // 32 B
    int*   nslots    = (int*)(ws + 36896);              // 4 B
    int*   slot_e_p  = (int*)(ws + 37120);              // 160 B
    int*   slot_rb_p = (int*)(ws + 37376);              // 160 B
    int*   tok_list  = (int*)(ws + 37632);              // 32768 B
    unsigned short* Yr  = (unsigned short*)(ws + 131072);                         // 40*64*1408*2 = 7208960 B
    unsigned short* Ysh = (unsigned short*)(ws + 131072 + (size_t)MAXSLOTS * 64 * IDIM * 2); // 1024*5632*2 B
    float* out_logits = out + (size_t)T_TOK * HDIM;

    hipMemsetAsync(counts, 0, 64, stream);
    hipMemsetAsync(out, 0, (size_t)T_TOK * HDIM * sizeof(float), stream);

    router_kernel<<<dim3(T_TOK), dim3(256), 0, stream>>>(
        hs, gw, sgw, out_logits, w_dense, sgate, counts, tok_list);
    slot_kernel<<<dim3(1), dim3(64), 0, stream>>>(counts, slot_e_p, slot_rb_p, nslots);
    gateup_kernel<<<dim3(SIDIM / 64, T_TOK / 64), dim3(256), 0, stream>>>(
        hs, swg, swu, 0LL, Ysh, SIDIM, HDIM,
        slot_e_p, slot_rb_p, counts, nslots, tok_list, 1);
    gateup_kernel<<<dim3(IDIM / 64, MAXSLOTS), dim3(256), 0, stream>>>(
        hs, wg, wu, (long long)HDIM * IDIM, Yr, IDIM, HDIM,
        slot_e_p, slot_rb_p, counts, nslots, tok_list, 0);
    down_kernel<<<dim3(HDIM / 64, T_TOK / 64), dim3(256), 0, stream>>>(
        Ysh, swd, 0LL, out, SIDIM,
        slot_e_p, slot_rb_p, counts, nslots, tok_list, w_dense, sgate, 1);
    down_kernel<<<dim3(HDIM / 64, MAXSLOTS), dim3(256), 0, stream>>>(
        Yr, wd, (long long)IDIM * HDIM, out, IDIM,
        slot_e_p, slot_rb_p, counts, nslots, tok_list, w_dense, sgate, 0);
}

// Round 2
// 752.955 us; speedup vs baseline: 1.0710x; 1.0710x over previous
//
#include <hip/hip_runtime.h>
#include <hip/hip_bf16.h>

#define T_TOK 1024
#define HDIM  2048
#define NEXP  8
#define IDIM  1408
#define SIDIM 5632
#define MAXSLOTS 24

typedef __attribute__((ext_vector_type(8))) short bf16x8;
typedef __attribute__((ext_vector_type(4))) float f32x4;

__device__ __forceinline__ unsigned f2bf(float x) {
    unsigned u = __float_as_uint(x);
    return (u + 0x7fffu + ((u >> 16) & 1u)) >> 16;
}

__device__ __forceinline__ void async16(const void* g, void* l) {
    __builtin_amdgcn_global_load_lds(
        (const __attribute__((address_space(1))) void*)g,
        (__attribute__((address_space(3))) void*)l, 16, 0, 0);
}

// ---------------- Convert X: fp32 -> bf16 flat ----------------
__global__ __launch_bounds__(256) void conv_x(
    const float* __restrict__ src, unsigned short* __restrict__ dst)
{
    const int i = blockIdx.x * 256 + threadIdx.x;   // handles 8 elems
    const float4* s = (const float4*)src + (size_t)i * 2;
    float4 a = s[0], b = s[1];
    union { unsigned short us[8]; uint4 v; } o;
    o.us[0] = (unsigned short)f2bf(a.x); o.us[1] = (unsigned short)f2bf(a.y);
    o.us[2] = (unsigned short)f2bf(a.z); o.us[3] = (unsigned short)f2bf(a.w);
    o.us[4] = (unsigned short)f2bf(b.x); o.us[5] = (unsigned short)f2bf(b.y);
    o.us[6] = (unsigned short)f2bf(b.z); o.us[7] = (unsigned short)f2bf(b.w);
    ((uint4*)dst)[i] = o.v;
}

// ---------------- Convert+transpose: src [K][N] f32 -> dst [N][K] bf16 ----------------
__global__ __launch_bounds__(256) void conv_t(
    const float* __restrict__ src, unsigned short* __restrict__ dst, int K, int N)
{
    const size_t zoff = (size_t)blockIdx.z * K * N;
    src += zoff; dst += zoff;
    const int n  = blockIdx.x * 64 + (threadIdx.x & 63);
    const int k0 = blockIdx.y * 64 + (threadIdx.x >> 6) * 16;
    union { unsigned short us[16]; uint4 v[2]; } o;
#pragma unroll
    for (int i = 0; i < 16; ++i)
        o.us[i] = (unsigned short)f2bf(src[(size_t)(k0 + i) * N + n]);
    uint4* d = (uint4*)(dst + (size_t)n * K + k0);
    d[0] = o.v[0]; d[1] = o.v[1];
}

// ---------------- Router: logits, softmax, top-2, token lists ----------------
__global__ __launch_bounds__(256) void router_kernel(
    const float* __restrict__ hs, const float* __restrict__ gw,
    const float* __restrict__ sgw, float* __restrict__ out_logits,
    float* __restrict__ w_dense, float* __restrict__ sgate,
    int* __restrict__ counts, int* __restrict__ tok_list)
{
    const int t = blockIdx.x;
    const int tid = threadIdx.x;
    const float* h = hs + (size_t)t * HDIM;
    float acc[9];
#pragma unroll
    for (int e = 0; e < 9; ++e) acc[e] = 0.f;
    for (int i = tid; i < HDIM; i += 256) {
        float hv = h[i];
        const float4* g4 = (const float4*)(gw + (size_t)i * NEXP);
        float4 g0 = g4[0], g1 = g4[1];
        acc[0] += hv * g0.x; acc[1] += hv * g0.y;
        acc[2] += hv * g0.z; acc[3] += hv * g0.w;
        acc[4] += hv * g1.x; acc[5] += hv * g1.y;
        acc[6] += hv * g1.z; acc[7] += hv * g1.w;
        acc[8] += hv * sgw[i];
    }
#pragma unroll
    for (int e = 0; e < 9; ++e)
        for (int off = 32; off > 0; off >>= 1)
            acc[e] += __shfl_down(acc[e], off, 64);
    __shared__ float lds[4][9];
    const int wid = tid >> 6, lane = tid & 63;
    if (lane == 0)
        for (int e = 0; e < 9; ++e) lds[wid][e] = acc[e];
    __syncthreads();
    if (tid == 0) {
        float l[9];
        for (int e = 0; e < 9; ++e)
            l[e] = lds[0][e] + lds[1][e] + lds[2][e] + lds[3][e];
        for (int e = 0; e < NEXP; ++e) out_logits[(size_t)t * NEXP + e] = l[e];
        float m = l[0];
        for (int e = 1; e < NEXP; ++e) m = fmaxf(m, l[e]);
        float p[NEXP], s = 0.f;
        for (int e = 0; e < NEXP; ++e) { p[e] = expf(l[e] - m); s += p[e]; }
        float inv = 1.f / s;
        for (int e = 0; e < NEXP; ++e) p[e] *= inv;
        int e0 = 0;
        for (int e = 1; e < NEXP; ++e) if (p[e] > p[e0]) e0 = e;
        int e1 = (e0 == 0) ? 1 : 0;
        for (int e = 0; e < NEXP; ++e) if (e != e0 && p[e] > p[e1]) e1 = e;
        for (int e = 0; e < NEXP; ++e)
            w_dense[(size_t)t * NEXP + e] = (e == e0) ? p[e0] : ((e == e1) ? p[e1] : 0.f);
        sgate[t] = 1.f / (1.f + expf(-l[8]));
        int p0 = atomicAdd(&counts[e0], 1); tok_list[e0 * T_TOK + p0] = t;
        int p1 = atomicAdd(&counts[e1], 1); tok_list[e1 * T_TOK + p1] = t;
    }
}

// ---------------- Slot table: per-expert 128-row M tiles ----------------
__global__ __launch_bounds__(64) void slot_kernel(
    const int* __restrict__ counts, int* __restrict__ slot_e,
    int* __restrict__ slot_rb, int* __restrict__ nslots)
{
    if (threadIdx.x == 0 && blockIdx.x == 0) {
        int ns = 0;
        for (int e = 0; e < NEXP; ++e)
            for (int b = 0; b < counts[e]; b += 128) {
                slot_e[ns] = e; slot_rb[ns] = b; ++ns;
            }
        nslots[0] = ns;
    }
}

// ---------------- Gate+Up GEMM: Y = silu(X@Wg^T) * (X@Wu^T), all bf16 ----------------
// Block tile M=128 x N=64 (per matrix), BK=32; 4 waves 2x2, wave = 64Mx32N.
// A LDS [m][k] chunked+swizzled, B LDS [n][k] same; staged via global_load_lds w16.
__global__ __launch_bounds__(256) void gateup2(
    const unsigned short* __restrict__ Xb,
    const unsigned short* __restrict__ WtG, const unsigned short* __restrict__ WtU,
    long long estride, unsigned short* __restrict__ Y, int N, int K,
    const int* __restrict__ slot_e, const int* __restrict__ slot_rb,
    const int* __restrict__ counts, const int* __restrict__ nslots,
    const int* __restrict__ tok_list, const unsigned short* __restrict__ zeropad,
    int mode)
{
    const int slot = blockIdx.y;
    if (mode == 0 && slot >= nslots[0]) return;
    const int n0 = blockIdx.x * 64;
    const int e = (mode == 0) ? slot_e[slot] : 0;
    const int rowbase = (mode == 0) ? slot_rb[slot] : 0;
    const unsigned short* __restrict__ Wg = WtG + (size_t)e * estride;
    const unsigned short* __restrict__ Wu = WtU + (size_t)e * estride;
    const int tid = threadIdx.x, lane = tid & 63, wid = tid >> 6;
    const int wr = (wid >> 1) * 64;
    const int wc = (wid & 1) * 32;
    const int fm = lane & 15, kg = lane >> 4;

    __shared__ int ltok[128];
    __shared__ __align__(16) unsigned short Xa[128 * 32];
    __shared__ __align__(16) unsigned short Bgs[64 * 32];
    __shared__ __align__(16) unsigned short Bus[64 * 32];

    if (tid < 128) {
        int tg;
        if (mode == 0) {
            int cnt = counts[e];
            tg = (rowbase + tid < cnt) ? tok_list[e * T_TOK + rowbase + tid] : -1;
        } else {
            tg = slot * 128 + tid;
        }
        ltok[tid] = tg;
    }
    __syncthreads();

    f32x4 ag[4][2], au[4][2];
#pragma unroll
    for (int a = 0; a < 4; ++a)
#pragma unroll
        for (int b = 0; b < 2; ++b) {
            ag[a][b] = f32x4{0.f, 0.f, 0.f, 0.f};
            au[a][b] = f32x4{0.f, 0.f, 0.f, 0.f};
        }

    // A staging lanes (2 issues/thread): chunk c -> row r=c>>2, k-sub kc=(c&3)^((r>>1)&3)
    const int cA0 = wid * 64 + lane, cA1 = (4 + wid) * 64 + lane;
    const int rA0 = cA0 >> 2, rA1 = cA1 >> 2;
    const int kA0 = ((cA0 & 3) ^ ((rA0 >> 1) & 3)) * 8;
    const int kA1 = ((cA1 & 3) ^ ((rA1 >> 1) & 3)) * 8;
    const int t0 = ltok[rA0], t1 = ltok[rA1];
    const unsigned short* xb0 = (t0 >= 0) ? Xb + (size_t)t0 * K + kA0 : zeropad;
    const unsigned short* xb1 = (t1 >= 0) ? Xb + (size_t)t1 * K + kA1 : zeropad;
    // B staging (1 issue per matrix)
    const int cB = wid * 64 + lane;
    const int rB = cB >> 2;
    const int kB = ((cB & 3) ^ ((rB >> 1) & 3)) * 8;
    const unsigned short* gb = Wg + (size_t)(n0 + rB) * K + kB;
    const unsigned short* ub = Wu + (size_t)(n0 + rB) * K + kB;

    for (int k0 = 0; k0 < K; k0 += 32) {
        async16(xb0 + (t0 >= 0 ? k0 : 0), &Xa[wid * 512]);
        async16(xb1 + (t1 >= 0 ? k0 : 0), &Xa[(4 + wid) * 512]);
        async16(gb + k0, &Bgs[wid * 512]);
        async16(ub + k0, &Bus[wid * 512]);
        __syncthreads();

        bf16x8 af[4];
#pragma unroll
        for (int mt = 0; mt < 4; ++mt) {
            const int r = wr + mt * 16 + fm;
            const int ch = r * 4 + (kg ^ ((r >> 1) & 3));
            af[mt] = *(const bf16x8*)&Xa[ch * 8];
        }
#pragma unroll
        for (int nt = 0; nt < 2; ++nt) {
            const int r = wc + nt * 16 + fm;
            const int ch = r * 4 + (kg ^ ((r >> 1) & 3));
            bf16x8 bg = *(const bf16x8*)&Bgs[ch * 8];
            bf16x8 bu = *(const bf16x8*)&Bus[ch * 8];
#pragma unroll
            for (int mt = 0; mt < 4; ++mt) {
                ag[mt][nt] = __builtin_amdgcn_mfma_f32_16x16x32_bf16(af[mt], bg, ag[mt][nt], 0, 0, 0);
                au[mt][nt] = __builtin_amdgcn_mfma_f32_16x16x32_bf16(af[mt], bu, au[mt][nt], 0, 0, 0);
            }
        }
        __syncthreads();
    }

#pragma unroll
    for (int mt = 0; mt < 4; ++mt)
#pragma unroll
        for (int nt = 0; nt < 2; ++nt) {
            const int col = n0 + wc + nt * 16 + fm;
#pragma unroll
            for (int i = 0; i < 4; ++i) {
                const int row = wr + mt * 16 + kg * 4 + i;
                float g = ag[mt][nt][i], u = au[mt][nt][i];
                float yv = g / (1.f + expf(-g)) * u;
                Y[(size_t)(slot * 128 + row) * N + col] = (unsigned short)f2bf(yv);
            }
        }
}

// ---------------- Down GEMM: out[tok] += w * (Y @ Wd^T) ----------------
// Block tile M=128 x N=128, BK=32; 4 waves 2x2, wave = 64x64. K split by blockIdx.z.
__global__ __launch_bounds__(256) void down2(
    const unsigned short* __restrict__ Yb, const unsigned short* __restrict__ WtD,
    long long estride, float* __restrict__ out, int K, int kchunk,
    const int* __restrict__ slot_e, const int* __restrict__ slot_rb,
    const int* __restrict__ counts, const int* __restrict__ nslots,
    const int* __restrict__ tok_list, const float* __restrict__ w_dense,
    const float* __restrict__ sgate, int mode)
{
    const int slot = blockIdx.y;
    if (mode == 0 && slot >= nslots[0]) return;
    const int n0 = blockIdx.x * 128;
    const int kbase = blockIdx.z * kchunk;
    const int e = (mode == 0) ? slot_e[slot] : 0;
    const int rowbase = (mode == 0) ? slot_rb[slot] : 0;
    const unsigned short* __restrict__ Wd = WtD + (size_t)e * estride;
    const int tid = threadIdx.x, lane = tid & 63, wid = tid >> 6;
    const int wr = (wid >> 1) * 64;
    const int wc = (wid & 1) * 64;
    const int fm = lane & 15, kg = lane >> 4;

    __shared__ int ltok[128];
    __shared__ float lw[128];
    __shared__ __align__(16) unsigned short Ya[128 * 32];
    __shared__ __align__(16) unsigned short Bd[128 * 32];

    if (tid < 128) {
        int tg; float wv;
        if (mode == 0) {
            int cnt = counts[e];
            if (rowbase + tid < cnt) {
                tg = tok_list[e * T_TOK + rowbase + tid];
                wv = w_dense[(size_t)tg * NEXP + e];
            } else { tg = -1; wv = 0.f; }
        } else {
            tg = slot * 128 + tid; wv = sgate[tg];
        }
        ltok[tid] = tg; lw[tid] = wv;
    }
    __syncthreads();

    f32x4 acc[4][4];
#pragma unroll
    for (int a = 0; a < 4; ++a)
#pragma unroll
        for (int b = 0; b < 4; ++b) acc[a][b] = f32x4{0.f, 0.f, 0.f, 0.f};

    const int c0 = wid * 64 + lane, c1 = (4 + wid) * 64 + lane;
    const int r0 = c0 >> 2, r1 = c1 >> 2;
    const int k0s = ((c0 & 3) ^ ((r0 >> 1) & 3)) * 8;
    const int k1s = ((c1 & 3) ^ ((r1 >> 1) & 3)) * 8;
    const unsigned short* ya0 = Yb + (size_t)(slot * 128 + r0) * K + k0s;
    const unsigned short* ya1 = Yb + (size_t)(slot * 128 + r1) * K + k1s;
    const unsigned short* wb0 = Wd + (size_t)(n0 + r0) * K + k0s;
    const unsigned short* wb1 = Wd + (size_t)(n0 + r1) * K + k1s;

    const int kend = kbase + kchunk;
    for (int k0 = kbase; k0 < kend; k0 += 32) {
        async16(ya0 + k0, &Ya[wid * 512]);
        async16(ya1 + k0, &Ya[(4 + wid) * 512]);
        async16(wb0 + k0, &Bd[wid * 512]);
        async16(wb1 + k0, &Bd[(4 + wid) * 512]);
        __syncthreads();

        bf16x8 af[4];
#pragma unroll
        for (int mt = 0; mt < 4; ++mt) {
            const int r = wr + mt * 16 + fm;
            const int ch = r * 4 + (kg ^ ((r >> 1) & 3));
            af[mt] = *(const bf16x8*)&Ya[ch * 8];
        }
#pragma unroll
        for (int nt = 0; nt < 4; ++nt) {
            const int r = wc + nt * 16 + fm;
            const int ch = r * 4 + (kg ^ ((r >> 1) & 3));
            bf16x8 bf = *(const bf16x8*)&Bd[ch * 8];
#pragma unroll
            for (int mt = 0; mt < 4; ++mt)
                acc[mt][nt] = __builtin_amdgcn_mfma_f32_16x16x32_bf16(af[mt], bf, acc[mt][nt], 0, 0, 0);
        }
        __syncthreads();
    }

#pragma unroll
    for (int mt = 0; mt < 4; ++mt)
#pragma unroll
        for (int nt = 0; nt < 4; ++nt) {
            const int col = n0 + wc + nt * 16 + fm;
#pragma unroll
            for (int i = 0; i < 4; ++i) {
                const int row = wr + mt * 16 + kg * 4 + i;
                const int tg = ltok[row];
                if (tg >= 0)
                    atomicAdd(out + (size_t)tg * HDIM + col, lw[row] * acc[mt][nt][i]);
            }
        }
}

extern "C" void kernel_launch(void* const* d_in, const int* in_sizes, int n_in,
                              void* d_out, int out_size, void* d_ws, size_t ws_size,
                              hipStream_t stream)
{
    const float* hs  = (const float*)d_in[0];
    const float* gw  = (const float*)d_in[1];
    const float* wg  = (const float*)d_in[2];
    const float* wu  = (const float*)d_in[3];
    const float* wd  = (const float*)d_in[4];
    const float* swg = (const float*)d_in[5];
    const float* swu = (const float*)d_in[6];
    const float* swd = (const float*)d_in[7];
    const float* sgw = (const float*)d_in[8];
    float* out = (float*)d_out;
    char* ws = (char*)d_ws;

    float* w_dense = (float*)(ws);
    float* sgate   = (float*)(ws + 32768);
    int* counts    = (int*)(ws + 36864);
    int* nslots    = (int*)(ws + 37120);
    unsigned short* zeropad = (unsigned short*)(ws + 37376);
    int* slot_e    = (int*)(ws + 37888);
    int* slot_rb   = (int*)(ws + 38144);
    int* tok_list  = (int*)(ws + 40960);
    unsigned short* Xb   = (unsigned short*)(ws + 131072);
    unsigned short* Yr   = (unsigned short*)(ws + 4325376);
    unsigned short* Ysh  = (unsigned short*)(ws + 12976128);
    unsigned short* wtg  = (unsigned short*)(ws + 24510464);
    unsigned short* wtu  = (unsigned short*)(ws + 70647808);
    unsigned short* wtd  = (unsigned short*)(ws + 116785152);
    unsigned short* swtg = (unsigned short*)(ws + 162922496);
    unsigned short* swtu = (unsigned short*)(ws + 185991168);
    unsigned short* swtd = (unsigned short*)(ws + 209059840);
    float* out_logits = out + (size_t)T_TOK * HDIM;

    hipMemsetAsync(counts, 0, 256, stream);
    hipMemsetAsync(zeropad, 0, 512, stream);
    hipMemsetAsync(out, 0, (size_t)T_TOK * HDIM * sizeof(float), stream);

    conv_x<<<dim3(1024), dim3(256), 0, stream>>>(hs, Xb);
    conv_t<<<dim3(22, 32, 8), dim3(256), 0, stream>>>(wg, wtg, 2048, 1408);
    conv_t<<<dim3(22, 32, 8), dim3(256), 0, stream>>>(wu, wtu, 2048, 1408);
    conv_t<<<dim3(32, 22, 8), dim3(256), 0, stream>>>(wd, wtd, 1408, 2048);
    conv_t<<<dim3(88, 32, 1), dim3(256), 0, stream>>>(swg, swtg, 2048, 5632);
    conv_t<<<dim3(88, 32, 1), dim3(256), 0, stream>>>(swu, swtu, 2048, 5632);
    conv_t<<<dim3(32, 88, 1), dim3(256), 0, stream>>>(swd, swtd, 5632, 2048);

    router_kernel<<<dim3(T_TOK), dim3(256), 0, stream>>>(
        hs, gw, sgw, out_logits, w_dense, sgate, counts, tok_list);
    slot_kernel<<<dim3(1), dim3(64), 0, stream>>>(counts, slot_e, slot_rb, nslots);

    gateup2<<<dim3(SIDIM / 64, T_TOK / 128), dim3(256), 0, stream>>>(
        Xb, swtg, swtu, 0LL, Ysh, SIDIM, HDIM,
        slot_e, slot_rb, counts, nslots, tok_list, zeropad, 1);
    gateup2<<<dim3(IDIM / 64, MAXSLOTS), dim3(256), 0, stream>>>(
        Xb, wtg, wtu, (long long)HDIM * IDIM, Yr, IDIM, HDIM,
        slot_e, slot_rb, counts, nslots, tok_list, zeropad, 0);

    down2<<<dim3(HDIM / 128, T_TOK / 128, 2), dim3(256), 0, stream>>>(
        Ysh, swtd, 0LL, out, SIDIM, SIDIM / 2,
        slot_e, slot_rb, counts, nslots, tok_list, w_dense, sgate, 1);
    down2<<<dim3(HDIM / 128, MAXSLOTS, 1), dim3(256), 0, stream>>>(
        Yr, wtd, (long long)IDIM * HDIM, out, IDIM, IDIM,
        slot_e, slot_rb, counts, nslots, tok_list, w_dense, sgate, 0);
}

// Round 3
// 652.948 us; speedup vs baseline: 1.2351x; 1.1532x over previous
//
#include <hip/hip_runtime.h>
#include <hip/hip_bf16.h>

#define T_TOK 1024
#define HDIM  2048
#define NEXP  8
#define IDIM  1408
#define SIDIM 5632
#define MAXSLOTS 24

typedef __attribute__((ext_vector_type(8))) short bf16x8;
typedef __attribute__((ext_vector_type(4))) float f32x4;
typedef unsigned short ushort_t;

__device__ __forceinline__ unsigned f2bf(float x) {
    unsigned u = __float_as_uint(x);
    return (u + 0x7fffu + ((u >> 16) & 1u)) >> 16;
}
__device__ __forceinline__ unsigned pack2(float a, float b) {
    return f2bf(a) | (f2bf(b) << 16);
}
__device__ __forceinline__ void async16(const void* g, void* l) {
    __builtin_amdgcn_global_load_lds(
        (const __attribute__((address_space(1))) void*)g,
        (__attribute__((address_space(3))) void*)l, 16, 0, 0);
}

// ---------------- Convert X: fp32 -> bf16 flat ----------------
__global__ __launch_bounds__(256) void conv_x(
    const float* __restrict__ src, ushort_t* __restrict__ dst)
{
    const int i = blockIdx.x * 256 + threadIdx.x;
    const float4* s = (const float4*)src + (size_t)i * 2;
    float4 a = s[0], b = s[1];
    union { ushort_t us[8]; uint4 v; } o;
    o.us[0] = (ushort_t)f2bf(a.x); o.us[1] = (ushort_t)f2bf(a.y);
    o.us[2] = (ushort_t)f2bf(a.z); o.us[3] = (ushort_t)f2bf(a.w);
    o.us[4] = (ushort_t)f2bf(b.x); o.us[5] = (ushort_t)f2bf(b.y);
    o.us[6] = (ushort_t)f2bf(b.z); o.us[7] = (ushort_t)f2bf(b.w);
    ((uint4*)dst)[i] = o.v;
}

// ------- Convert+transpose all weights: [K][N] f32 -> [N][K] bf16, one launch -------
// 64x64 tiles via LDS (coalesced reads AND writes). Grid = 25344 tiles.
__global__ __launch_bounds__(256) void conv_all(
    const float* __restrict__ wg, const float* __restrict__ wu,
    const float* __restrict__ wd, const float* __restrict__ swg,
    const float* __restrict__ swu, const float* __restrict__ swd,
    ushort_t* __restrict__ wtg, ushort_t* __restrict__ wtu,
    ushort_t* __restrict__ wtd, ushort_t* __restrict__ swtg,
    ushort_t* __restrict__ swtu, ushort_t* __restrict__ swtd)
{
    int id = blockIdx.x;
    const float* src; ushort_t* dst; int K, N, ktile, ntile;
    if (id < 11264) {
        const float* s0; ushort_t* d0;
        if (id < 5632) { s0 = wg; d0 = wtg; } else { s0 = wu; d0 = wtu; id -= 5632; }
        const int e = id / 704, t = id % 704;
        K = 2048; N = 1408;
        src = s0 + (size_t)e * K * N; dst = d0 + (size_t)e * K * N;
        ntile = t % 22; ktile = t / 22;
    } else if (id < 16896) {
        const int t2 = id - 11264;
        const int e = t2 / 704, t = t2 % 704;
        K = 1408; N = 2048;
        src = wd + (size_t)e * K * N; dst = wtd + (size_t)e * K * N;
        ntile = t % 32; ktile = t / 32;
    } else if (id < 22528) {
        int t2 = id - 16896; const float* s0; ushort_t* d0;
        if (t2 < 2816) { s0 = swg; d0 = swtg; } else { s0 = swu; d0 = swtu; t2 -= 2816; }
        K = 2048; N = 5632;
        src = s0; dst = d0;
        ntile = t2 % 88; ktile = t2 / 88;
    } else {
        const int t2 = id - 22528;
        K = 5632; N = 2048; src = swd; dst = swtd;
        ntile = t2 % 32; ktile = t2 / 32;
    }
    const int tid = threadIdx.x;
    __shared__ unsigned ldsw[64 * 33];
    const float* sp = src + (size_t)(ktile * 64) * N + ntile * 64;
    const int n = tid & 63;
    const int p0 = (tid >> 6) * 8;
#pragma unroll
    for (int j = 0; j < 8; ++j) {
        const int p = p0 + j;
        float a = sp[(size_t)(2 * p) * N + n];
        float b = sp[(size_t)(2 * p + 1) * N + n];
        ldsw[n * 33 + p] = pack2(a, b);
    }
    __syncthreads();
    ushort_t* dp = dst + (size_t)(ntile * 64) * K + ktile * 64;
#pragma unroll
    for (int j = 0; j < 2; ++j) {
        const int c = tid + j * 256;
        const int row = c >> 3, kc = c & 7;
        const unsigned* lw_ = &ldsw[row * 33 + kc * 4];
        uint4 v; v.x = lw_[0]; v.y = lw_[1]; v.z = lw_[2]; v.w = lw_[3];
        *(uint4*)(dp + (size_t)row * K + kc * 8) = v;
    }
}

// ---------------- Router ----------------
__global__ __launch_bounds__(256) void router_kernel(
    const float* __restrict__ hs, const float* __restrict__ gw,
    const float* __restrict__ sgw, float* __restrict__ out_logits,
    float* __restrict__ w_dense, float* __restrict__ sgate,
    int* __restrict__ counts, int* __restrict__ tok_list)
{
    const int t = blockIdx.x;
    const int tid = threadIdx.x;
    const float* h = hs + (size_t)t * HDIM;
    float acc[9];
#pragma unroll
    for (int e = 0; e < 9; ++e) acc[e] = 0.f;
    for (int i = tid; i < HDIM; i += 256) {
        float hv = h[i];
        const float4* g4 = (const float4*)(gw + (size_t)i * NEXP);
        float4 g0 = g4[0], g1 = g4[1];
        acc[0] += hv * g0.x; acc[1] += hv * g0.y;
        acc[2] += hv * g0.z; acc[3] += hv * g0.w;
        acc[4] += hv * g1.x; acc[5] += hv * g1.y;
        acc[6] += hv * g1.z; acc[7] += hv * g1.w;
        acc[8] += hv * sgw[i];
    }
#pragma unroll
    for (int e = 0; e < 9; ++e)
        for (int off = 32; off > 0; off >>= 1)
            acc[e] += __shfl_down(acc[e], off, 64);
    __shared__ float lds[4][9];
    const int wid = tid >> 6, lane = tid & 63;
    if (lane == 0)
        for (int e = 0; e < 9; ++e) lds[wid][e] = acc[e];
    __syncthreads();
    if (tid == 0) {
        float l[9];
        for (int e = 0; e < 9; ++e)
            l[e] = lds[0][e] + lds[1][e] + lds[2][e] + lds[3][e];
        for (int e = 0; e < NEXP; ++e) out_logits[(size_t)t * NEXP + e] = l[e];
        float m = l[0];
        for (int e = 1; e < NEXP; ++e) m = fmaxf(m, l[e]);
        float p[NEXP], s = 0.f;
        for (int e = 0; e < NEXP; ++e) { p[e] = expf(l[e] - m); s += p[e]; }
        float inv = 1.f / s;
        for (int e = 0; e < NEXP; ++e) p[e] *= inv;
        int e0 = 0;
        for (int e = 1; e < NEXP; ++e) if (p[e] > p[e0]) e0 = e;
        int e1 = (e0 == 0) ? 1 : 0;
        for (int e = 0; e < NEXP; ++e) if (e != e0 && p[e] > p[e1]) e1 = e;
        for (int e = 0; e < NEXP; ++e)
            w_dense[(size_t)t * NEXP + e] = (e == e0) ? p[e0] : ((e == e1) ? p[e1] : 0.f);
        sgate[t] = 1.f / (1.f + expf(-l[8]));
        int p0 = atomicAdd(&counts[e0], 1); tok_list[e0 * T_TOK + p0] = t;
        int p1 = atomicAdd(&counts[e1], 1); tok_list[e1 * T_TOK + p1] = t;
    }
}

__global__ __launch_bounds__(64) void slot_kernel(
    const int* __restrict__ counts, int* __restrict__ slot_e,
    int* __restrict__ slot_rb, int* __restrict__ nslots)
{
    if (threadIdx.x == 0 && blockIdx.x == 0) {
        int ns = 0;
        for (int e = 0; e < NEXP; ++e)
            for (int b = 0; b < counts[e]; b += 128) {
                slot_e[ns] = e; slot_rb[ns] = b; ++ns;
            }
        nslots[0] = ns;
    }
}

// ---- Gate+Up merged (shared + routed): block 128M x 64N(x2 mats), BK=64 ----
// blocks [0,704): shared; [704, 704+22*MAXSLOTS): routed
__global__ __launch_bounds__(256) void gateup_all(
    const ushort_t* __restrict__ Xb,
    const ushort_t* __restrict__ swtg, const ushort_t* __restrict__ swtu,
    const ushort_t* __restrict__ wtg, const ushort_t* __restrict__ wtu,
    ushort_t* __restrict__ Ysh, ushort_t* __restrict__ Yr,
    const int* __restrict__ slot_e, const int* __restrict__ slot_rb,
    const int* __restrict__ counts, const int* __restrict__ nslots,
    const int* __restrict__ tok_list, const ushort_t* __restrict__ zerobuf)
{
    const int id = blockIdx.x;
    int n0, slot, e, rowbase, N, mode;
    if (id < 704) {
        mode = 1; n0 = (id % 88) * 64; slot = id / 88; e = 0; rowbase = 0; N = SIDIM;
    } else {
        mode = 0;
        const int id2 = id - 704;
        n0 = (id2 % 22) * 64; slot = id2 / 22;
        if (slot >= nslots[0]) return;
        e = slot_e[slot]; rowbase = slot_rb[slot]; N = IDIM;
    }
    const ushort_t* __restrict__ Wg = mode ? swtg : wtg + (size_t)e * HDIM * IDIM;
    const ushort_t* __restrict__ Wu = mode ? swtu : wtu + (size_t)e * HDIM * IDIM;
    ushort_t* __restrict__ Y = mode ? Ysh : Yr;
    const int K = HDIM;

    const int tid = threadIdx.x, lane = tid & 63, wid = tid >> 6;
    const int wr = (wid >> 1) * 64;
    const int wc = (wid & 1) * 32;
    const int fm = lane & 15, kg = lane >> 4;

    __shared__ int ltok[128];
    __shared__ __align__(16) ushort_t Xa[128 * 64];
    __shared__ __align__(16) ushort_t Bgs[64 * 64];
    __shared__ __align__(16) ushort_t Bus[64 * 64];

    if (tid < 128) {
        int tg;
        if (mode == 0) {
            int cnt = counts[e];
            tg = (rowbase + tid < cnt) ? tok_list[e * T_TOK + rowbase + tid] : -1;
        } else {
            tg = slot * 128 + tid;
        }
        ltok[tid] = tg;
    }
    __syncthreads();

    f32x4 ag[4][2], au[4][2];
#pragma unroll
    for (int a = 0; a < 4; ++a)
#pragma unroll
        for (int b = 0; b < 2; ++b) {
            ag[a][b] = f32x4{0.f, 0.f, 0.f, 0.f};
            au[a][b] = f32x4{0.f, 0.f, 0.f, 0.f};
        }

    // per-thread swizzled k-offset (same for every issue)
    const int koff = (((tid & 7) ^ ((tid >> 3) & 7))) * 8;
    const ushort_t* pA[4];
#pragma unroll
    for (int j = 0; j < 4; ++j) {
        const int r = (tid >> 3) + j * 32;
        const int tk = ltok[r];
        pA[j] = (tk >= 0) ? Xb + (size_t)tk * K + koff : zerobuf;
    }
    const ushort_t* pG[2];
    const ushort_t* pU[2];
#pragma unroll
    for (int j = 0; j < 2; ++j) {
        const int r = (tid >> 3) + j * 32;
        pG[j] = Wg + (size_t)(n0 + r) * K + koff;
        pU[j] = Wu + (size_t)(n0 + r) * K + koff;
    }

    for (int k0 = 0; k0 < K; k0 += 64) {
#pragma unroll
        for (int j = 0; j < 4; ++j)
            async16(pA[j] + k0, &Xa[(j * 256 + wid * 64) * 8]);
#pragma unroll
        for (int j = 0; j < 2; ++j) {
            async16(pG[j] + k0, &Bgs[(j * 256 + wid * 64) * 8]);
            async16(pU[j] + k0, &Bus[(j * 256 + wid * 64) * 8]);
        }
        __syncthreads();

#pragma unroll
        for (int ks = 0; ks < 2; ++ks) {
            const int kx = ((ks * 4 + kg) ^ (fm & 7)) * 8;
            bf16x8 af[4];
#pragma unroll
            for (int mt = 0; mt < 4; ++mt)
                af[mt] = *(const bf16x8*)&Xa[(wr + mt * 16 + fm) * 64 + kx];
#pragma unroll
            for (int nt = 0; nt < 2; ++nt) {
                const int rb = (wc + nt * 16 + fm) * 64 + kx;
                bf16x8 bg = *(const bf16x8*)&Bgs[rb];
                bf16x8 bu = *(const bf16x8*)&Bus[rb];
#pragma unroll
                for (int mt = 0; mt < 4; ++mt) {
                    ag[mt][nt] = __builtin_amdgcn_mfma_f32_16x16x32_bf16(af[mt], bg, ag[mt][nt], 0, 0, 0);
                    au[mt][nt] = __builtin_amdgcn_mfma_f32_16x16x32_bf16(af[mt], bu, au[mt][nt], 0, 0, 0);
                }
            }
        }
        __syncthreads();
    }

#pragma unroll
    for (int mt = 0; mt < 4; ++mt)
#pragma unroll
        for (int nt = 0; nt < 2; ++nt) {
            const int col = n0 + wc + nt * 16 + fm;
#pragma unroll
            for (int i = 0; i < 4; ++i) {
                const int row = wr + mt * 16 + kg * 4 + i;
                float g = ag[mt][nt][i], u = au[mt][nt][i];
                float yv = g / (1.f + expf(-g)) * u;
                Y[(size_t)(slot * 128 + row) * N + col] = (ushort_t)f2bf(yv);
            }
        }
}

// ---- Down merged (shared z-split 4 + routed z-split 2): 128M x 128N, BK=64 ----
// blocks [0,512): shared (16n x 8m x 4z); [512, 512+16*MAXSLOTS*2): routed
__global__ __launch_bounds__(256) void down_all(
    const ushort_t* __restrict__ Ysh, const ushort_t* __restrict__ Yr,
    const ushort_t* __restrict__ swtd, const ushort_t* __restrict__ wtd,
    float* __restrict__ out,
    const int* __restrict__ slot_e, const int* __restrict__ slot_rb,
    const int* __restrict__ counts, const int* __restrict__ nslots,
    const int* __restrict__ tok_list, const float* __restrict__ w_dense,
    const float* __restrict__ sgate)
{
    const int id = blockIdx.x;
    int n0, slot, e, rowbase, K, kbase, ksteps, mode;
    const ushort_t* Yb;
    const ushort_t* Wd;
    if (id < 512) {
        mode = 1;
        n0 = (id & 15) * 128; slot = (id >> 4) & 7;
        const int z = id >> 7;
        K = SIDIM; kbase = z * 1408; ksteps = 22;
        e = 0; rowbase = 0;
        Yb = Ysh + (size_t)slot * 128 * K;
        Wd = swtd;
    } else {
        mode = 0;
        const int id2 = id - 512;
        n0 = (id2 & 15) * 128;
        const int rest = id2 >> 4;
        slot = rest >> 1;
        if (slot >= nslots[0]) return;
        const int z = rest & 1;
        K = IDIM; kbase = z * 704; ksteps = 11;
        e = slot_e[slot]; rowbase = slot_rb[slot];
        Yb = Yr + (size_t)slot * 128 * K;
        Wd = wtd + (size_t)e * IDIM * HDIM;
    }
    const int tid = threadIdx.x, lane = tid & 63, wid = tid >> 6;
    const int wr = (wid >> 1) * 64;
    const int wc = (wid & 1) * 64;
    const int fm = lane & 15, kg = lane >> 4;

    __shared__ int ltok[128];
    __shared__ float lw[128];
    __shared__ __align__(16) ushort_t Ya[128 * 64];
    __shared__ __align__(16) ushort_t Bd[128 * 64];

    if (tid < 128) {
        int tg; float wv;
        if (mode == 0) {
            int cnt = counts[e];
            if (rowbase + tid < cnt) {
                tg = tok_list[e * T_TOK + rowbase + tid];
                wv = w_dense[(size_t)tg * NEXP + e];
            } else { tg = -1; wv = 0.f; }
        } else {
            tg = slot * 128 + tid; wv = sgate[tg];
        }
        ltok[tid] = tg; lw[tid] = wv;
    }
    __syncthreads();

    f32x4 acc[4][4];
#pragma unroll
    for (int a = 0; a < 4; ++a)
#pragma unroll
        for (int b = 0; b < 4; ++b) acc[a][b] = f32x4{0.f, 0.f, 0.f, 0.f};

    const int koff = (((tid & 7) ^ ((tid >> 3) & 7))) * 8;
    const ushort_t* pY[4];
    const ushort_t* pW[4];
#pragma unroll
    for (int j = 0; j < 4; ++j) {
        const int r = (tid >> 3) + j * 32;
        pY[j] = Yb + (size_t)r * K + kbase + koff;
        pW[j] = Wd + (size_t)(n0 + r) * K + kbase + koff;
    }

    for (int s = 0; s < ksteps; ++s) {
        const int k0 = s * 64;
#pragma unroll
        for (int j = 0; j < 4; ++j) {
            async16(pY[j] + k0, &Ya[(j * 256 + wid * 64) * 8]);
            async16(pW[j] + k0, &Bd[(j * 256 + wid * 64) * 8]);
        }
        __syncthreads();

#pragma unroll
        for (int ks = 0; ks < 2; ++ks) {
            const int kx = ((ks * 4 + kg) ^ (fm & 7)) * 8;
            bf16x8 af[4];
#pragma unroll
            for (int mt = 0; mt < 4; ++mt)
                af[mt] = *(const bf16x8*)&Ya[(wr + mt * 16 + fm) * 64 + kx];
#pragma unroll
            for (int nt = 0; nt < 4; ++nt) {
                bf16x8 bf = *(const bf16x8*)&Bd[(wc + nt * 16 + fm) * 64 + kx];
#pragma unroll
                for (int mt = 0; mt < 4; ++mt)
                    acc[mt][nt] = __builtin_amdgcn_mfma_f32_16x16x32_bf16(af[mt], bf, acc[mt][nt], 0, 0, 0);
            }
        }
        __syncthreads();
    }

#pragma unroll
    for (int mt = 0; mt < 4; ++mt)
#pragma unroll
        for (int nt = 0; nt < 4; ++nt) {
            const int col = n0 + wc + nt * 16 + fm;
#pragma unroll
            for (int i = 0; i < 4; ++i) {
                const int row = wr + mt * 16 + kg * 4 + i;
                const int tg = ltok[row];
                if (tg >= 0)
                    atomicAdd(out + (size_t)tg * HDIM + col, lw[row] * acc[mt][nt][i]);
            }
        }
}

extern "C" void kernel_launch(void* const* d_in, const int* in_sizes, int n_in,
                              void* d_out, int out_size, void* d_ws, size_t ws_size,
                              hipStream_t stream)
{
    const float* hs  = (const float*)d_in[0];
    const float* gw  = (const float*)d_in[1];
    const float* wg  = (const float*)d_in[2];
    const float* wu  = (const float*)d_in[3];
    const float* wd  = (const float*)d_in[4];
    const float* swg = (const float*)d_in[5];
    const float* swu = (const float*)d_in[6];
    const float* swd = (const float*)d_in[7];
    const float* sgw = (const float*)d_in[8];
    float* out = (float*)d_out;
    char* ws = (char*)d_ws;

    float* w_dense      = (float*)(ws + 0x00000);
    float* sgate        = (float*)(ws + 0x08000);
    int* counts         = (int*)(ws + 0x09000);
    int* nslots         = (int*)(ws + 0x09100);
    int* slot_e         = (int*)(ws + 0x09200);
    int* slot_rb        = (int*)(ws + 0x09300);
    int* tok_list       = (int*)(ws + 0x09400);
    ushort_t* zerobuf   = (ushort_t*)(ws + 0x11400);   // 16 KB zeros
    ushort_t* Xb        = (ushort_t*)(ws + 0x20000);
    ushort_t* Yr        = (ushort_t*)(ws + 0x420000);
    ushort_t* Ysh       = (ushort_t*)(ws + 0xC60000);
    ushort_t* wtg       = (ushort_t*)(ws + 0x1760000);
    ushort_t* wtu       = (ushort_t*)(ws + 0x4360000);
    ushort_t* wtd       = (ushort_t*)(ws + 0x6F60000);
    ushort_t* swtg      = (ushort_t*)(ws + 0x9B60000);
    ushort_t* swtu      = (ushort_t*)(ws + 0xB160000);
    ushort_t* swtd      = (ushort_t*)(ws + 0xC760000);
    float* out_logits = out + (size_t)T_TOK * HDIM;

    hipMemsetAsync(counts, 0, 256, stream);
    hipMemsetAsync(zerobuf, 0, 16384, stream);
    hipMemsetAsync(out, 0, (size_t)T_TOK * HDIM * sizeof(float), stream);

    conv_x<<<dim3(1024), dim3(256), 0, stream>>>(hs, Xb);
    conv_all<<<dim3(25344), dim3(256), 0, stream>>>(
        wg, wu, wd, swg, swu, swd, wtg, wtu, wtd, swtg, swtu, swtd);

    router_kernel<<<dim3(T_TOK), dim3(256), 0, stream>>>(
        hs, gw, sgw, out_logits, w_dense, sgate, counts, tok_list);
    slot_kernel<<<dim3(1), dim3(64), 0, stream>>>(counts, slot_e, slot_rb, nslots);

    gateup_all<<<dim3(704 + 22 * MAXSLOTS), dim3(256), 0, stream>>>(
        Xb, swtg, swtu, wtg, wtu, Ysh, Yr,
        slot_e, slot_rb, counts, nslots, tok_list, zerobuf);

    down_all<<<dim3(512 + 16 * MAXSLOTS * 2), dim3(256), 0, stream>>>(
        Ysh, Yr, swtd, wtd, out,
        slot_e, slot_rb, counts, nslots, tok_list, w_dense, sgate);
}